// Round 7
// baseline (183.553 us; speedup 1.0000x reference)
//
#include <hip/hip_runtime.h>
#include <hip/hip_bf16.h>

// Causal attention, B=2 NH=16 T=2048 D=64, fp32 I/O.
// R19 = R16 inner loop (single-V, permlane P, CEXP-folded Kb, setprio) with a
// GRID RESTRUCTURE for real TLP: one block per (bh, q-tile) -> 1024 blocks,
// 4 waves split the tile's 2j+2 key-tiles, proven LDS end-combine.
//   * 48 KB/block x 1024 blocks -> 3 blocks/CU resident = 12 waves/CU
//     = 3 waves/SIMD (was 2: 512 blocks could never exceed 2 blocks/CU).
//   * __launch_bounds__(256,3): reg cap ~170 >> current ~124, no spill risk.
//   * heavy/light pairing, parked state, kTileOf wrap all deleted.
//   * dispatch order j = 31 - gid/32: biggest blocks (64 tiles) first.
// R18 post-mortem: cross-step skew = regression (sa live-range -> 128-reg
// cliff, no issue-count reduction); ILP attempts exhausted, TLP was the lever.

typedef __bf16 bf16;
typedef __bf16 bf16x2 __attribute__((ext_vector_type(2)));
typedef __bf16 bf16x4 __attribute__((ext_vector_type(4)));
typedef __bf16 bf16x8 __attribute__((ext_vector_type(8)));
typedef float floatx4 __attribute__((ext_vector_type(4)));

#define T_SEQ 2048
#define DH 64
#define TKS 32
#define BHN 32
#define CEXP 0.18033688011112042f  // (1/sqrt(64)) * log2(e)

__device__ __forceinline__ void gload16(const bf16* g, bf16* l) {
    __builtin_amdgcn_global_load_lds(
        (const __attribute__((address_space(1))) void*)g,
        (__attribute__((address_space(3))) void*)l, 16, 0, 0);
}

// ---------------- fused prepass (CEXP folded into Kb) ----------------
__global__ __launch_bounds__(256) void prep(const float* __restrict__ K,
                                            const float* __restrict__ V,
                                            bf16* __restrict__ Kb,
                                            bf16* __restrict__ Vt) {
    const int bid = (int)blockIdx.x;
    const int tid = (int)threadIdx.x;
    if (bid < 512) {
        size_t i = ((size_t)bid * 256 + tid) * 8;
        #pragma unroll
        for (int it = 0; it < 4; ++it) {
            float4 a = *(const float4*)(K + i + 0);
            float4 b = *(const float4*)(K + i + 4);
            bf16x8 o;
            o[0]=(bf16)(a.x*CEXP); o[1]=(bf16)(a.y*CEXP); o[2]=(bf16)(a.z*CEXP); o[3]=(bf16)(a.w*CEXP);
            o[4]=(bf16)(b.x*CEXP); o[5]=(bf16)(b.y*CEXP); o[6]=(bf16)(b.z*CEXP); o[7]=(bf16)(b.w*CEXP);
            *(bf16x8*)(Kb + i) = o;
            i += (size_t)512 * 256 * 8;
        }
        return;
    }
    __shared__ bf16 tile[2][64][72];
    const int vb = bid - 512;
    const int bh = vb & (BHN - 1);
    const int tp = (vb >> 5) * 128;
    #pragma unroll
    for (int tt = 0; tt < 2; ++tt) {
        const int r = tid >> 2;
        const int c = (tid & 3) * 16;
        const float* s = V + ((size_t)bh * T_SEQ + tp + tt * 64 + r) * DH + c;
        float4 f0 = *(const float4*)(s + 0);
        float4 f1 = *(const float4*)(s + 4);
        float4 f2 = *(const float4*)(s + 8);
        float4 f3 = *(const float4*)(s + 12);
        bf16x8 p0, p1;
        p0[0]=(bf16)f0.x; p0[1]=(bf16)f0.y; p0[2]=(bf16)f0.z; p0[3]=(bf16)f0.w;
        p0[4]=(bf16)f1.x; p0[5]=(bf16)f1.y; p0[6]=(bf16)f1.z; p0[7]=(bf16)f1.w;
        p1[0]=(bf16)f2.x; p1[1]=(bf16)f2.y; p1[2]=(bf16)f2.z; p1[3]=(bf16)f2.w;
        p1[4]=(bf16)f3.x; p1[5]=(bf16)f3.y; p1[6]=(bf16)f3.z; p1[7]=(bf16)f3.w;
        *(bf16x8*)&tile[tt][r][c + 0] = p0;
        *(bf16x8*)&tile[tt][r][c + 8] = p1;
    }
    __syncthreads();
    #pragma unroll
    for (int tt = 0; tt < 2; ++tt) {
        const int d   = tid >> 2;
        const int tch = (tid & 3) * 16;
        bf16x8 o0, o1;
        #pragma unroll
        for (int j = 0; j < 8; ++j) { o0[j] = tile[tt][tch + j][d]; o1[j] = tile[tt][tch + 8 + j][d]; }
        bf16* o = Vt + ((size_t)bh * DH + d) * T_SEQ + tp + tt * 64 + tch;
        *(bf16x8*)(o + 0) = o0;
        *(bf16x8*)(o + 8) = o1;
    }
}

// ---------------- main flash kernel ----------------
// Grid: 1024 blocks = (bh 0..31) x (q-tile j 0..31), dispatched big-j first.
// Per-wave LDS (bf16 elems, 6144 = 12 KB): K0@0, K1@2048, V@4096 (single buf).
// K tile [32 key][64 d]: row = 8x16B chunks, slot c of row r = global chunk c^(r&7).
// V tile [64 d][32 k]: row = 4x16B chunks, slot c of row r = global chunk c^((r>>1)&3).
// MFMA 16x16x32: A[m=l16][k=quad*8+j], B[k=quad*8+j][n=l16], C/D col=l16,row=quad*4+r.
__global__ __launch_bounds__(256, 3)
void fa_fwd(const float* __restrict__ Qg, const bf16* __restrict__ Kb,
            const bf16* __restrict__ Vt, float* __restrict__ Og)
{
    __shared__ __align__(16) bf16 smem[24576];   // 48 KB = 4 waves x 12 KB

    const int gid   = (int)blockIdx.x;
    const int jt    = 31 - (gid >> 5);           // q-tile index, big first
    const int bh    = gid & (BHN - 1);
    const int qbase = jt * 64;
    const int ntile = 2 * jt + 2;                // causal key-tiles for this q-tile

    const int tid  = (int)threadIdx.x;
    const int wave = tid >> 6;
    const int lane = tid & 63;
    const int quad = lane >> 4;
    const int l16  = lane & 15;
    const int psw  = (l16 >> 1) & 3;

    // balanced strip split of [0, ntile) over 4 waves; empty waves allowed
    const int base = ntile >> 2;
    const int rem  = ntile & 3;
    const int tw0  = wave * base + ((wave < rem) ? wave : rem);
    const int cnt  = base + ((wave < rem) ? 1 : 0);
    const int tw1  = tw0 + cnt;

    bf16* W = smem + wave * 6144;

    const bf16* Kbh = Kb + (size_t)bh * (T_SEQ * DH);
    const bf16* Vbh = Vt + (size_t)bh * (DH * T_SEQ);
    const size_t qrb = (size_t)bh * T_SEQ;

    // staging lane constants
    const int rl  = lane >> 3;
    const int kch = (lane & 7) ^ (rl & 7);
    const int vr  = lane >> 2;
    const int vch = (lane & 3) ^ ((lane >> 3) & 3);

    floatx4 oacc[4][4];
    #pragma unroll
    for (int mt = 0; mt < 4; ++mt)
        #pragma unroll
        for (int nt = 0; nt < 4; ++nt) oacc[mt][nt] = (floatx4){0.f,0.f,0.f,0.f};
    float lpart[4] = {0.f, 0.f, 0.f, 0.f};

    auto stageK = [&](int kt, bf16* dst) {
        const bf16* kg = Kbh + (size_t)kt * TKS * DH;
        #pragma unroll
        for (int g = 0; g < 4; ++g)
            gload16(kg + (size_t)(g * 8 + rl) * DH + kch * 8, dst + g * 512);
    };
    auto stageV = [&](int kt, bf16* dst) {
        const bf16* vg = Vbh + kt * TKS;
        #pragma unroll
        for (int g = 0; g < 4; ++g)
            gload16(vg + (size_t)(g * 16 + vr) * T_SEQ + vch * 8, dst + g * 512);
    };

    // pack 2 fp32 -> 1 dword of 2 bf16 (compiler fuses to v_cvt_pk_bf16_f32)
    auto pk2 = [&](float a, float b) -> unsigned {
        bf16x2 h; h[0] = (bf16)a; h[1] = (bf16)b;
        return __builtin_bit_cast(unsigned, h);
    };

    if (cnt > 0) {
        // Q fragments for this block's q-tile (all waves load the same tile;
        // redundant but L2-resident)
        bf16x8 qb[4][2];
        #pragma unroll
        for (int nt = 0; nt < 4; ++nt) {
            const int qrow = qbase + nt * 16 + l16;
            #pragma unroll
            for (int kk = 0; kk < 2; ++kk) {
                const float* s = Qg + (qrb + qrow) * DH + kk * 32 + quad * 8;
                float4 f0 = *(const float4*)(s);
                float4 f1 = *(const float4*)(s + 4);
                bf16x8 t;
                t[0]=(bf16)f0.x; t[1]=(bf16)f0.y; t[2]=(bf16)f0.z; t[3]=(bf16)f0.w;
                t[4]=(bf16)f1.x; t[5]=(bf16)f1.y; t[6]=(bf16)f1.z; t[7]=(bf16)f1.w;
                qb[nt][kk] = t;
            }
        }

        stageK(tw0, W);
        stageV(tw0, W + 4096);

        for (int t = tw0; t < tw1; ++t) {
            const int cur = (t - tw0) & 1;
            bf16* Kcur = W + cur * 2048;
            bf16* Vcur = W + 4096;               // single V buffer
            const int k0 = t * TKS;

            const bool pf = (t + 1 < tw1);
            if (pf) {                            // prefetch K(t+1) into alt buffer
                stageK(t + 1, W + (cur ^ 1) * 2048);
                __builtin_amdgcn_s_waitcnt(0x0F78);  // vmcnt(8): K(t) landed
            } else {
                __builtin_amdgcn_s_waitcnt(0x0F70);  // vmcnt(0): everything landed
            }

            // ---- S^T = K.Q^T ----
            floatx4 sa[2][4];
            #pragma unroll
            for (int mt = 0; mt < 2; ++mt)
                #pragma unroll
                for (int nt = 0; nt < 4; ++nt) sa[mt][nt] = (floatx4){0.f,0.f,0.f,0.f};
            __builtin_amdgcn_s_setprio(1);
            #pragma unroll
            for (int kk = 0; kk < 2; ++kk) {
                #pragma unroll
                for (int mt = 0; mt < 2; ++mt) {
                    bf16x8 kf = *(const bf16x8*)&Kcur[(mt * 16 + l16) * 64 + (((kk * 4 + quad) ^ (l16 & 7)) * 8)];
                    #pragma unroll
                    for (int nt = 0; nt < 4; ++nt)
                        sa[mt][nt] = __builtin_amdgcn_mfma_f32_16x16x32_bf16(kf, qb[nt][kk], sa[mt][nt], 0, 0, 0);
                }
            }
            __builtin_amdgcn_s_setprio(0);
            // ---- causal mask (only the last two tiles touch the band) ----
            if (k0 + TKS - 1 > qbase) {
                #pragma unroll
                for (int mt = 0; mt < 2; ++mt)
                    #pragma unroll
                    for (int nt = 0; nt < 4; ++nt) {
                        const int qg = qbase + nt * 16 + l16;
                        #pragma unroll
                        for (int r = 0; r < 4; ++r) {
                            const int keyg = k0 + mt * 16 + quad * 4 + r;
                            if (keyg > qg) sa[mt][nt][r] = -INFINITY;
                        }
                    }
            }
            // ---- exp2 + in-register P^T build (permlane exchange) ----
            bf16x8 pfr[4];
            #pragma unroll
            for (int nt = 0; nt < 4; ++nt) {
                float p0[4], p1[4];
                #pragma unroll
                for (int r = 0; r < 4; ++r) {
                    p0[r] = __builtin_amdgcn_exp2f(sa[0][nt][r]);
                    p1[r] = __builtin_amdgcn_exp2f(sa[1][nt][r]);
                    lpart[nt] += p0[r] + p1[r];
                }
                unsigned X0 = pk2(p0[0], p0[1]);     // mt0, d0
                unsigned X1 = pk2(p0[2], p0[3]);     // mt0, d1
                unsigned Y0 = pk2(p1[0], p1[1]);     // mt1, d0
                unsigned Y1 = pk2(p1[2], p1[3]);     // mt1, d1
                asm("v_permlane32_swap_b32 %0, %1" : "+v"(X0), "+v"(Y0));
                asm("v_permlane16_swap_b32 %0, %1" : "+v"(X0), "+v"(Y0));
                asm("v_permlane32_swap_b32 %0, %1" : "+v"(X1), "+v"(Y1));
                asm("v_permlane16_swap_b32 %0, %1" : "+v"(X1), "+v"(Y1));
                uint4 u; u.x = X0; u.y = X1; u.z = Y0; u.w = Y1;
                pfr[nt] = __builtin_bit_cast(bf16x8, u);
            }
            // ---- V frags to regs, then stage V(t+1) into the SAME buffer ----
            if (pf) __builtin_amdgcn_s_waitcnt(0x0F74);  // vmcnt(4): V(t) landed
            bf16x8 vf[4];
            #pragma unroll
            for (int mt = 0; mt < 4; ++mt)
                vf[mt] = *(const bf16x8*)&Vcur[(mt * 16 + l16) * 32 + ((quad ^ psw) * 8)];
            if (pf) {
                __builtin_amdgcn_s_waitcnt(0xC07F);      // lgkmcnt(0): vf in regs
                stageV(t + 1, Vcur);                     // safe: V(t) consumed
            }
            // ---- O^T += V^T.P^T ----
            __builtin_amdgcn_s_setprio(1);
            #pragma unroll
            for (int mt = 0; mt < 4; ++mt) {
                #pragma unroll
                for (int nt = 0; nt < 4; ++nt)
                    oacc[mt][nt] = __builtin_amdgcn_mfma_f32_16x16x32_bf16(vf[mt], pfr[nt], oacc[mt][nt], 0, 0, 0);
            }
            __builtin_amdgcn_s_setprio(0);
        }
    }

    // ================= end combine: 4 partials of ONE q-tile =================
    // All 4 waves dump (area = wave, 4608 bf16 elems = 9216 B, 4 areas = 36 KB).
    // Waves 0,1 sum all areas; wave0 finishes nt 0..1, wave1 nt 2..3.
    __syncthreads();
    {
        bf16* a = smem + wave * 4608;
        float* al = (float*)(a + 4096);
        #pragma unroll
        for (int f = 0; f < 16; ++f) {
            bf16x4 w;
            #pragma unroll
            for (int e = 0; e < 4; ++e) w[e] = (bf16)oacc[f >> 2][f & 3][e];
            *(bf16x4*)&a[(f * 64 + lane) * 4] = w;
        }
        #pragma unroll
        for (int nt = 0; nt < 4; ++nt)
            al[nt * 64 + lane] = lpart[nt];
    }
    __syncthreads();

    if (wave <= 1) {
        #pragma unroll
        for (int mt = 0; mt < 4; ++mt)
            #pragma unroll
            for (int nt = 0; nt < 4; ++nt) oacc[mt][nt] = (floatx4){0.f,0.f,0.f,0.f};
        #pragma unroll
        for (int nt = 0; nt < 4; ++nt) lpart[nt] = 0.f;
        for (int i = 0; i < 4; ++i) {
            const bf16* a = smem + i * 4608;
            const float* al = (const float*)(a + 4096);
            #pragma unroll
            for (int f = 0; f < 16; ++f) {
                bf16x4 w = *(const bf16x4*)&a[(f * 64 + lane) * 4];
                #pragma unroll
                for (int e = 0; e < 4; ++e) oacc[f >> 2][f & 3][e] += (float)w[e];
            }
            #pragma unroll
            for (int nt = 0; nt < 4; ++nt) lpart[nt] += al[nt * 64 + lane];
        }
        const int nt0 = wave * 2;                // wave0: nt 0,1; wave1: nt 2,3
        float invl[2];
        #pragma unroll
        for (int k = 0; k < 2; ++k) {
            float v = lpart[nt0 + k];
            v += __shfl_xor(v, 16);
            v += __shfl_xor(v, 32);
            invl[k] = 1.0f / v;
        }
        #pragma unroll
        for (int k = 0; k < 2; ++k) {
            const int nt = nt0 + k;
            const size_t qrow = qrb + qbase + nt * 16 + l16;
            #pragma unroll
            for (int mt = 0; mt < 4; ++mt) {
                float4 o;
                o.x = oacc[mt][nt][0] * invl[k];
                o.y = oacc[mt][nt][1] * invl[k];
                o.z = oacc[mt][nt][2] * invl[k];
                o.w = oacc[mt][nt][3] * invl[k];
                *(float4*)&Og[qrow * DH + mt * 16 + quad * 4] = o;
            }
        }
    }
}

extern "C" void kernel_launch(void* const* d_in, const int* in_sizes, int n_in,
                              void* d_out, int out_size, void* d_ws, size_t ws_size,
                              hipStream_t stream) {
    const float* Q = (const float*)d_in[0];
    const float* K = (const float*)d_in[1];
    const float* V = (const float*)d_in[2];
    float* O = (float*)d_out;
    (void)in_sizes; (void)n_in; (void)out_size; (void)ws_size;

    const size_t nelem = (size_t)BHN * T_SEQ * DH;   // 4,194,304
    bf16* Kbf = (bf16*)d_ws;            // 8 MiB
    bf16* Vtb = Kbf + nelem;            // 8 MiB

    prep<<<dim3(1024), dim3(256), 0, stream>>>(K, V, Kbf, Vtb);
    fa_fwd<<<dim3(1024), dim3(256), 0, stream>>>(Q, Kbf, Vtb, O);
}

// Round 8
// 127.636 us; speedup vs baseline: 1.4381x; 1.4381x over previous
//
#include <hip/hip_runtime.h>
#include <hip/hip_bf16.h>

// Causal attention, B=2 NH=16 T=2048 D=64, fp32 I/O.
// R20 = R19 grid (1024 blocks = bh x q-tile, big-j first) with the per-wave
// tile HALVED to 32 q-rows so the register state (~135 unified regs) fits
// 3 waves/SIMD WITHOUT spills (R13/R19 failed because 64-row state = ~188
// regs > 512/3 cap -> spill cliff; the occupancy gain was real, 15->27%).
//   * waves {0,1}: q-rows 0-31 of the tile, key range split in two
//     waves {2,3}: q-rows 32-63 likewise
//   * lower half skips the last key tile (fully masked for its rows)
//   * R16 inner loop verbatim (single-V, permlane P, vmcnt(8)/(4) ledger --
//     4 loads per stage, ledger identical)
//   * 2-way pairwise combine per q-half (s=1 dumps, s=0 sums+writes)
// Tripwire: WRITE_SIZE must stay ~16.4 MB (no scratch); VGPR ~95-110.

typedef __bf16 bf16;
typedef __bf16 bf16x2 __attribute__((ext_vector_type(2)));
typedef __bf16 bf16x4 __attribute__((ext_vector_type(4)));
typedef __bf16 bf16x8 __attribute__((ext_vector_type(8)));
typedef float floatx4 __attribute__((ext_vector_type(4)));

#define T_SEQ 2048
#define DH 64
#define TKS 32
#define BHN 32
#define CEXP 0.18033688011112042f  // (1/sqrt(64)) * log2(e)

__device__ __forceinline__ void gload16(const bf16* g, bf16* l) {
    __builtin_amdgcn_global_load_lds(
        (const __attribute__((address_space(1))) void*)g,
        (__attribute__((address_space(3))) void*)l, 16, 0, 0);
}

// ---------------- fused prepass (CEXP folded into Kb) ----------------
__global__ __launch_bounds__(256) void prep(const float* __restrict__ K,
                                            const float* __restrict__ V,
                                            bf16* __restrict__ Kb,
                                            bf16* __restrict__ Vt) {
    const int bid = (int)blockIdx.x;
    const int tid = (int)threadIdx.x;
    if (bid < 512) {
        size_t i = ((size_t)bid * 256 + tid) * 8;
        #pragma unroll
        for (int it = 0; it < 4; ++it) {
            float4 a = *(const float4*)(K + i + 0);
            float4 b = *(const float4*)(K + i + 4);
            bf16x8 o;
            o[0]=(bf16)(a.x*CEXP); o[1]=(bf16)(a.y*CEXP); o[2]=(bf16)(a.z*CEXP); o[3]=(bf16)(a.w*CEXP);
            o[4]=(bf16)(b.x*CEXP); o[5]=(bf16)(b.y*CEXP); o[6]=(bf16)(b.z*CEXP); o[7]=(bf16)(b.w*CEXP);
            *(bf16x8*)(Kb + i) = o;
            i += (size_t)512 * 256 * 8;
        }
        return;
    }
    __shared__ bf16 tile[2][64][72];
    const int vb = bid - 512;
    const int bh = vb & (BHN - 1);
    const int tp = (vb >> 5) * 128;
    #pragma unroll
    for (int tt = 0; tt < 2; ++tt) {
        const int r = tid >> 2;
        const int c = (tid & 3) * 16;
        const float* s = V + ((size_t)bh * T_SEQ + tp + tt * 64 + r) * DH + c;
        float4 f0 = *(const float4*)(s + 0);
        float4 f1 = *(const float4*)(s + 4);
        float4 f2 = *(const float4*)(s + 8);
        float4 f3 = *(const float4*)(s + 12);
        bf16x8 p0, p1;
        p0[0]=(bf16)f0.x; p0[1]=(bf16)f0.y; p0[2]=(bf16)f0.z; p0[3]=(bf16)f0.w;
        p0[4]=(bf16)f1.x; p0[5]=(bf16)f1.y; p0[6]=(bf16)f1.z; p0[7]=(bf16)f1.w;
        p1[0]=(bf16)f2.x; p1[1]=(bf16)f2.y; p1[2]=(bf16)f2.z; p1[3]=(bf16)f2.w;
        p1[4]=(bf16)f3.x; p1[5]=(bf16)f3.y; p1[6]=(bf16)f3.z; p1[7]=(bf16)f3.w;
        *(bf16x8*)&tile[tt][r][c + 0] = p0;
        *(bf16x8*)&tile[tt][r][c + 8] = p1;
    }
    __syncthreads();
    #pragma unroll
    for (int tt = 0; tt < 2; ++tt) {
        const int d   = tid >> 2;
        const int tch = (tid & 3) * 16;
        bf16x8 o0, o1;
        #pragma unroll
        for (int j = 0; j < 8; ++j) { o0[j] = tile[tt][tch + j][d]; o1[j] = tile[tt][tch + 8 + j][d]; }
        bf16* o = Vt + ((size_t)bh * DH + d) * T_SEQ + tp + tt * 64 + tch;
        *(bf16x8*)(o + 0) = o0;
        *(bf16x8*)(o + 8) = o1;
    }
}

// ---------------- main flash kernel ----------------
// Grid: 1024 blocks = (bh 0..31) x (q-tile j 0..31), big-j first.
// Block: q-tile j (64 rows). wave = 2*half + s: half = q-rows [32*half,32*half+32),
// s splits that half's causal key range [0, 2j+1+half) in two strips.
// Per-wave LDS (bf16 elems, 6144 = 12 KB): K0@0, K1@2048, V@4096 (single buf).
// K tile [32 key][64 d]: row = 8x16B chunks, slot c of row r = global chunk c^(r&7).
// V tile [64 d][32 k]: row = 4x16B chunks, slot c of row r = global chunk c^((r>>1)&3).
// MFMA 16x16x32: A[m=l16][k=quad*8+j], B[k=quad*8+j][n=l16], C/D col=l16,row=quad*4+r.
__global__ __launch_bounds__(256, 3)
void fa_fwd(const float* __restrict__ Qg, const bf16* __restrict__ Kb,
            const bf16* __restrict__ Vt, float* __restrict__ Og)
{
    __shared__ __align__(16) bf16 smem[24576];   // 48 KB = 4 waves x 12 KB

    const int gid   = (int)blockIdx.x;
    const int jt    = 31 - (gid >> 5);           // q-tile index, big first
    const int bh    = gid & (BHN - 1);

    const int tid  = (int)threadIdx.x;
    const int wave = tid >> 6;
    const int lane = tid & 63;
    const int quad = lane >> 4;
    const int l16  = lane & 15;
    const int psw  = (l16 >> 1) & 3;

    const int hf = wave >> 1;                    // q-half (0: rows 0-31, 1: 32-63)
    const int sp = wave & 1;                     // key-strip index within the pair

    const int qbaseW = jt * 64 + hf * 32;        // wave's lowest q-row
    const int ntileW = 2 * jt + 1 + hf;          // causal key tiles for this half
    const int c0  = (ntileW + 1) >> 1;
    const int tw0 = sp ? c0 : 0;
    const int tw1 = sp ? ntileW : c0;
    const int cnt = tw1 - tw0;                   // sp=0 always >=1; sp=1 may be 0

    bf16* W = smem + wave * 6144;

    const bf16* Kbh = Kb + (size_t)bh * (T_SEQ * DH);
    const bf16* Vbh = Vt + (size_t)bh * (DH * T_SEQ);
    const size_t qrb = (size_t)bh * T_SEQ;

    // staging lane constants
    const int rl  = lane >> 3;
    const int kch = (lane & 7) ^ (rl & 7);
    const int vr  = lane >> 2;
    const int vch = (lane & 3) ^ ((lane >> 3) & 3);

    floatx4 oacc[4][2];
    #pragma unroll
    for (int mt = 0; mt < 4; ++mt)
        #pragma unroll
        for (int nt = 0; nt < 2; ++nt) oacc[mt][nt] = (floatx4){0.f,0.f,0.f,0.f};
    float lpart[2] = {0.f, 0.f};

    auto stageK = [&](int kt, bf16* dst) {
        const bf16* kg = Kbh + (size_t)kt * TKS * DH;
        #pragma unroll
        for (int g = 0; g < 4; ++g)
            gload16(kg + (size_t)(g * 8 + rl) * DH + kch * 8, dst + g * 512);
    };
    auto stageV = [&](int kt, bf16* dst) {
        const bf16* vg = Vbh + kt * TKS;
        #pragma unroll
        for (int g = 0; g < 4; ++g)
            gload16(vg + (size_t)(g * 16 + vr) * T_SEQ + vch * 8, dst + g * 512);
    };

    // pack 2 fp32 -> 1 dword of 2 bf16 (compiler fuses to v_cvt_pk_bf16_f32)
    auto pk2 = [&](float a, float b) -> unsigned {
        bf16x2 h; h[0] = (bf16)a; h[1] = (bf16)b;
        return __builtin_bit_cast(unsigned, h);
    };

    if (cnt > 0) {
        // Q fragments: 32 rows (nt 0,1) of this wave's half
        bf16x8 qb[2][2];
        #pragma unroll
        for (int nt = 0; nt < 2; ++nt) {
            const int qrow = qbaseW + nt * 16 + l16;
            #pragma unroll
            for (int kk = 0; kk < 2; ++kk) {
                const float* s = Qg + (qrb + qrow) * DH + kk * 32 + quad * 8;
                float4 f0 = *(const float4*)(s);
                float4 f1 = *(const float4*)(s + 4);
                bf16x8 t;
                t[0]=(bf16)f0.x; t[1]=(bf16)f0.y; t[2]=(bf16)f0.z; t[3]=(bf16)f0.w;
                t[4]=(bf16)f1.x; t[5]=(bf16)f1.y; t[6]=(bf16)f1.z; t[7]=(bf16)f1.w;
                qb[nt][kk] = t;
            }
        }

        stageK(tw0, W);
        stageV(tw0, W + 4096);

        for (int t = tw0; t < tw1; ++t) {
            const int cur = (t - tw0) & 1;
            bf16* Kcur = W + cur * 2048;
            bf16* Vcur = W + 4096;               // single V buffer
            const int k0 = t * TKS;

            const bool pf = (t + 1 < tw1);
            if (pf) {                            // prefetch K(t+1) into alt buffer
                stageK(t + 1, W + (cur ^ 1) * 2048);
                __builtin_amdgcn_s_waitcnt(0x0F78);  // vmcnt(8): K(t) landed
            } else {
                __builtin_amdgcn_s_waitcnt(0x0F70);  // vmcnt(0): everything landed
            }

            // ---- S^T = K.Q^T (8 MFMA) ----
            floatx4 sa[2][2];
            #pragma unroll
            for (int mt = 0; mt < 2; ++mt)
                #pragma unroll
                for (int nt = 0; nt < 2; ++nt) sa[mt][nt] = (floatx4){0.f,0.f,0.f,0.f};
            __builtin_amdgcn_s_setprio(1);
            #pragma unroll
            for (int kk = 0; kk < 2; ++kk) {
                #pragma unroll
                for (int mt = 0; mt < 2; ++mt) {
                    bf16x8 kf = *(const bf16x8*)&Kcur[(mt * 16 + l16) * 64 + (((kk * 4 + quad) ^ (l16 & 7)) * 8)];
                    #pragma unroll
                    for (int nt = 0; nt < 2; ++nt)
                        sa[mt][nt] = __builtin_amdgcn_mfma_f32_16x16x32_bf16(kf, qb[nt][kk], sa[mt][nt], 0, 0, 0);
                }
            }
            __builtin_amdgcn_s_setprio(0);
            // ---- causal mask (diagonal band only) ----
            if (k0 + TKS - 1 > qbaseW) {
                #pragma unroll
                for (int mt = 0; mt < 2; ++mt)
                    #pragma unroll
                    for (int nt = 0; nt < 2; ++nt) {
                        const int qg = qbaseW + nt * 16 + l16;
                        #pragma unroll
                        for (int r = 0; r < 4; ++r) {
                            const int keyg = k0 + mt * 16 + quad * 4 + r;
                            if (keyg > qg) sa[mt][nt][r] = -INFINITY;
                        }
                    }
            }
            // ---- exp2 + in-register P^T build (permlane exchange) ----
            bf16x8 pfr[2];
            #pragma unroll
            for (int nt = 0; nt < 2; ++nt) {
                float p0[4], p1[4];
                #pragma unroll
                for (int r = 0; r < 4; ++r) {
                    p0[r] = __builtin_amdgcn_exp2f(sa[0][nt][r]);
                    p1[r] = __builtin_amdgcn_exp2f(sa[1][nt][r]);
                    lpart[nt] += p0[r] + p1[r];
                }
                unsigned X0 = pk2(p0[0], p0[1]);     // mt0, d0
                unsigned X1 = pk2(p0[2], p0[3]);     // mt0, d1
                unsigned Y0 = pk2(p1[0], p1[1]);     // mt1, d0
                unsigned Y1 = pk2(p1[2], p1[3]);     // mt1, d1
                asm("v_permlane32_swap_b32 %0, %1" : "+v"(X0), "+v"(Y0));
                asm("v_permlane16_swap_b32 %0, %1" : "+v"(X0), "+v"(Y0));
                asm("v_permlane32_swap_b32 %0, %1" : "+v"(X1), "+v"(Y1));
                asm("v_permlane16_swap_b32 %0, %1" : "+v"(X1), "+v"(Y1));
                uint4 u; u.x = X0; u.y = X1; u.z = Y0; u.w = Y1;
                pfr[nt] = __builtin_bit_cast(bf16x8, u);
            }
            // ---- V frags to regs, then stage V(t+1) into the SAME buffer ----
            if (pf) __builtin_amdgcn_s_waitcnt(0x0F74);  // vmcnt(4): V(t) landed
            bf16x8 vf[4];
            #pragma unroll
            for (int mt = 0; mt < 4; ++mt)
                vf[mt] = *(const bf16x8*)&Vcur[(mt * 16 + l16) * 32 + ((quad ^ psw) * 8)];
            if (pf) {
                __builtin_amdgcn_s_waitcnt(0xC07F);      // lgkmcnt(0): vf in regs
                stageV(t + 1, Vcur);                     // safe: V(t) consumed
            }
            // ---- O^T += V^T.P^T (8 MFMA) ----
            __builtin_amdgcn_s_setprio(1);
            #pragma unroll
            for (int mt = 0; mt < 4; ++mt) {
                #pragma unroll
                for (int nt = 0; nt < 2; ++nt)
                    oacc[mt][nt] = __builtin_amdgcn_mfma_f32_16x16x32_bf16(vf[mt], pfr[nt], oacc[mt][nt], 0, 0, 0);
            }
            __builtin_amdgcn_s_setprio(0);
        }
    }

    // ======== end combine: 2 partials per q-half (pairwise) ========
    // Area[hf]: 8 frags x 64 lanes x 4 bf16 = 4096 elems + 2x64 f32 = 4608 elems.
    // sp=1 dumps (zeros if cnt==0); sp=0 sums, normalizes, writes its 32 rows.
    __syncthreads();
    if (sp == 1) {
        bf16* a = smem + hf * 4608;
        float* al = (float*)(a + 4096);
        #pragma unroll
        for (int f = 0; f < 8; ++f) {
            bf16x4 w;
            #pragma unroll
            for (int e = 0; e < 4; ++e) w[e] = (bf16)oacc[f >> 1][f & 1][e];
            *(bf16x4*)&a[(f * 64 + lane) * 4] = w;
        }
        #pragma unroll
        for (int nt = 0; nt < 2; ++nt)
            al[nt * 64 + lane] = lpart[nt];
    }
    __syncthreads();
    if (sp == 0) {
        const bf16* a = smem + hf * 4608;
        const float* al = (const float*)(a + 4096);
        #pragma unroll
        for (int f = 0; f < 8; ++f) {
            bf16x4 w = *(const bf16x4*)&a[(f * 64 + lane) * 4];
            #pragma unroll
            for (int e = 0; e < 4; ++e) oacc[f >> 1][f & 1][e] += (float)w[e];
        }
        #pragma unroll
        for (int nt = 0; nt < 2; ++nt) lpart[nt] += al[nt * 64 + lane];

        float invl[2];
        #pragma unroll
        for (int nt = 0; nt < 2; ++nt) {
            float v = lpart[nt];
            v += __shfl_xor(v, 16);
            v += __shfl_xor(v, 32);
            invl[nt] = 1.0f / v;
        }
        #pragma unroll
        for (int nt = 0; nt < 2; ++nt) {
            const size_t qrow = qrb + qbaseW + nt * 16 + l16;
            #pragma unroll
            for (int mt = 0; mt < 4; ++mt) {
                float4 o;
                o.x = oacc[mt][nt][0] * invl[nt];
                o.y = oacc[mt][nt][1] * invl[nt];
                o.z = oacc[mt][nt][2] * invl[nt];
                o.w = oacc[mt][nt][3] * invl[nt];
                *(float4*)&Og[qrow * DH + mt * 16 + quad * 4] = o;
            }
        }
    }
}

extern "C" void kernel_launch(void* const* d_in, const int* in_sizes, int n_in,
                              void* d_out, int out_size, void* d_ws, size_t ws_size,
                              hipStream_t stream) {
    const float* Q = (const float*)d_in[0];
    const float* K = (const float*)d_in[1];
    const float* V = (const float*)d_in[2];
    float* O = (float*)d_out;
    (void)in_sizes; (void)n_in; (void)out_size; (void)ws_size;

    const size_t nelem = (size_t)BHN * T_SEQ * DH;   // 4,194,304
    bf16* Kbf = (bf16*)d_ws;            // 8 MiB
    bf16* Vtb = Kbf + nelem;            // 8 MiB

    prep<<<dim3(1024), dim3(256), 0, stream>>>(K, V, Kbf, Vtb);
    fa_fwd<<<dim3(1024), dim3(256), 0, stream>>>(Q, Kbf, Vtb, O);
}